// Round 5
// baseline (269.593 us; speedup 1.0000x reference)
//
#include <hip/hip_runtime.h>

// ---------------------------------------------------------------------------
// MultiheadAttentionWithAttention: y = Wo(attn(Wq q, Wk k, Wv v)) + bo,
// plus head-mean attention map. B=4, T=T_MEM=1024, C=1024, H=16, hd=64.
//
// Pipeline (bf16 MFMA, fp32 accum):
//   1. cvt_in3 / cvt_w4: fp32->bf16 (Wq pre-scaled by 1/8)
//   2. QKV projections: batched 128x128 gemm_bt with global_load_lds staging
//   3. transpose V to [b,h,d,t]
//   4. attn_q32: 1024 thr (16 waves), block = (b, 32 q-rows, hg of 8 heads),
//      grid 256 = 1 block/CU, grp->XCD affinity (K/V head-group slice stays
//      in its XCD's L2; 2x less L2 traffic than 16-row blocks).
//      Per head: QK^T into 32 regs -> softmax fully in registers (shfl over
//      l15 + RedM/RedS cross-wave) -> P (bf16) to LDS once -> PV split-K 2
//      with Yred reduce. amean: 32 plain-float regs/thread (static idx; the
//      r4 __half2 array went to SCRATCH at VGPR=56 - that was the 139us).
//      4 barriers/head.
//   5. mean2: attm = partial[hg0] + partial[hg1]  (fp32)
//   6. output projection -> fp32 d_out
//
// ws layout (MB), 56 MB total:
//   [0,24)  xin bf16 (q,k,v)  -> after gemm_qkv: [0,16) Pmean, [16,24) Vt
//   [24,32) W bf16 in order Wo,Wq,Wk,Wv
//   [32,56) Qp,Kp,Vp          -> Vp slot [48,56) becomes Ybf after transpose
// ---------------------------------------------------------------------------

typedef __attribute__((ext_vector_type(8))) short s16x8;
typedef __attribute__((ext_vector_type(4))) float f32x4;
typedef __attribute__((ext_vector_type(4))) unsigned short u16x4;

#define N_EMBD 1024
#define NH 16
#define BT 4096  // B*T flattened rows
#define STR 1032 // P row stride (elements)

#if __has_builtin(__builtin_amdgcn_global_load_lds)
#define HAVE_GLL 1
#define GLDS16(g, l)                                                              \
  __builtin_amdgcn_global_load_lds((__attribute__((address_space(1))) void*)(g), \
                                   (__attribute__((address_space(3))) void*)(l), 16, 0, 0)
#else
#define HAVE_GLL 0
#endif

static __device__ __forceinline__ unsigned short f2bf(float f) {
  unsigned int u = __builtin_bit_cast(unsigned int, f);
  u += 0x7FFFu + ((u >> 16) & 1u);  // RNE
  return (unsigned short)(u >> 16);
}
static __device__ __forceinline__ float bf2f(unsigned short h) {
  return __builtin_bit_cast(float, ((unsigned int)h) << 16);
}

// ---------------- fp32 -> bf16 converts (batched) ----------------
__global__ __launch_bounds__(256) void cvt_in3(const float* __restrict__ q,
                                               const float* __restrict__ k,
                                               const float* __restrict__ v,
                                               unsigned short* __restrict__ out) {
  const int z = blockIdx.z;
  const float* src = (z == 0) ? q : (z == 1 ? k : v);
  int i = (blockIdx.x * 256 + threadIdx.x) * 4;
  float4 val = *(const float4*)(src + i);
  u16x4 o;
  o[0] = f2bf(val.x);
  o[1] = f2bf(val.y);
  o[2] = f2bf(val.z);
  o[3] = f2bf(val.w);
  *(u16x4*)(out + (size_t)z * BT * N_EMBD + i) = o;
}

__global__ __launch_bounds__(256) void cvt_w4(const float* __restrict__ wo,
                                              const float* __restrict__ wq,
                                              const float* __restrict__ wk,
                                              const float* __restrict__ wv,
                                              unsigned short* __restrict__ out) {
  const int z = blockIdx.z;
  const float* src = (z == 0) ? wo : (z == 1 ? wq : (z == 2 ? wk : wv));
  const float scale = (z == 1) ? 0.125f : 1.0f;  // fold 1/sqrt(hd) into Wq
  int i = (blockIdx.x * 256 + threadIdx.x) * 4;
  float4 val = *(const float4*)(src + i);
  u16x4 o;
  o[0] = f2bf(val.x * scale);
  o[1] = f2bf(val.y * scale);
  o[2] = f2bf(val.z * scale);
  o[3] = f2bf(val.w * scale);
  *(u16x4*)(out + (size_t)z * N_EMBD * N_EMBD + i) = o;
}

// ---------------- 128x128 bf16 MFMA tile: C = A * B^T + bias ----------------
template <bool F32OUT>
static __device__ __forceinline__ void gemm_bt_tile(const unsigned short* __restrict__ A,
                                                    const unsigned short* __restrict__ B,
                                                    const float* __restrict__ bias, float bscale,
                                                    void* __restrict__ Cout,
                                                    int m0, int n0, int N, int K,
                                                    unsigned short* Al, unsigned short* Bl) {
  const int tid = threadIdx.x;
  const int l = tid & 63, w = tid >> 6;
  const int wr = w >> 1, wc = w & 1;
  const int l15 = l & 15, l4 = l >> 4;
  const int srow = tid >> 3;          // staging row within 32-row chunk
  const int skk = (tid & 7) * 8;      // staging k offset (16B)
  f32x4 acc[4][4] = {};
  for (int k0 = 0; k0 < K; k0 += 64) {
#if HAVE_GLL
#pragma unroll
    for (int i = 0; i < 4; ++i) {
      GLDS16(&A[(size_t)(m0 + i * 32 + srow) * K + k0 + skk], Al + i * 2048 + w * 512);
      GLDS16(&B[(size_t)(n0 + i * 32 + srow) * K + k0 + skk], Bl + i * 2048 + w * 512);
    }
#else
#pragma unroll
    for (int i = 0; i < 4; ++i) {
      int row = i * 32 + srow;
      *(s16x8*)&Al[row * 64 + skk] = *(const s16x8*)&A[(size_t)(m0 + row) * K + k0 + skk];
      *(s16x8*)&Bl[row * 64 + skk] = *(const s16x8*)&B[(size_t)(n0 + row) * K + k0 + skk];
    }
#endif
    __syncthreads();
#pragma unroll
    for (int kf = 0; kf < 2; ++kf) {
      s16x8 af[4], bfr[4];
#pragma unroll
      for (int mi = 0; mi < 4; ++mi)
        af[mi] = *(const s16x8*)&Al[(wr * 64 + mi * 16 + l15) * 64 + kf * 32 + l4 * 8];
#pragma unroll
      for (int nj = 0; nj < 4; ++nj)
        bfr[nj] = *(const s16x8*)&Bl[(wc * 64 + nj * 16 + l15) * 64 + kf * 32 + l4 * 8];
#pragma unroll
      for (int mi = 0; mi < 4; ++mi) {
#pragma unroll
        for (int nj = 0; nj < 4; ++nj)
          acc[mi][nj] =
              __builtin_amdgcn_mfma_f32_16x16x32_bf16(af[mi], bfr[nj], acc[mi][nj], 0, 0, 0);
      }
    }
    __syncthreads();
  }
#pragma unroll
  for (int nj = 0; nj < 4; ++nj) {
    int col = n0 + wc * 64 + nj * 16 + l15;
    float bv = bias[col] * bscale;
#pragma unroll
    for (int mi = 0; mi < 4; ++mi) {
#pragma unroll
      for (int r = 0; r < 4; ++r) {
        int row = m0 + wr * 64 + mi * 16 + l4 * 4 + r;
        float v = acc[mi][nj][r] + bv;
        if constexpr (F32OUT)
          ((float*)Cout)[(size_t)row * N + col] = v;
        else
          ((unsigned short*)Cout)[(size_t)row * N + col] = f2bf(v);
      }
    }
  }
}

// Batched QKV projection: grid.z selects q/k/v. Weights ordered Wo,Wq,Wk,Wv.
__global__ __launch_bounds__(256) void gemm_qkv(const unsigned short* __restrict__ Xin,
                                                const unsigned short* __restrict__ Wbf,
                                                const float* __restrict__ bq,
                                                const float* __restrict__ bk,
                                                const float* __restrict__ bv,
                                                unsigned short* __restrict__ Cout) {
  __shared__ unsigned short Al[128 * 64];
  __shared__ unsigned short Bl[128 * 64];
  const int z = blockIdx.z;
  const float* bias = (z == 0) ? bq : (z == 1 ? bk : bv);
  const float bscale = (z == 0) ? 0.125f : 1.0f;
  gemm_bt_tile<false>(Xin + (size_t)z * BT * N_EMBD,
                      Wbf + (size_t)(1 + z) * N_EMBD * N_EMBD, bias, bscale,
                      Cout + (size_t)z * BT * N_EMBD, blockIdx.x * 128, blockIdx.y * 128,
                      N_EMBD, N_EMBD, Al, Bl);
}

__global__ __launch_bounds__(256) void gemm_out(const unsigned short* __restrict__ Ybf,
                                                const unsigned short* __restrict__ Wo,
                                                const float* __restrict__ bo,
                                                float* __restrict__ Cout) {
  __shared__ unsigned short Al[128 * 64];
  __shared__ unsigned short Bl[128 * 64];
  gemm_bt_tile<true>(Ybf, Wo, bo, 1.0f, Cout, blockIdx.x * 128, blockIdx.y * 128, N_EMBD, N_EMBD,
                     Al, Bl);
}

// ---------------- V transpose: Vp[b,t,h*64+d] -> Vt[(b,h),d,t] ----------------
__global__ __launch_bounds__(256) void transpose_v(const unsigned short* __restrict__ Vp,
                                                   unsigned short* __restrict__ Vt) {
  __shared__ unsigned short tile[64][65];
  const int t0 = blockIdx.x * 64, h = blockIdx.y, b = blockIdx.z;
  const int r = threadIdx.x >> 2, c0 = (threadIdx.x & 3) * 16;
  const unsigned short* src = Vp + (size_t)(b * 1024 + t0 + r) * 1024 + h * 64 + c0;
#pragma unroll
  for (int j = 0; j < 16; ++j) tile[r][c0 + j] = src[j];
  __syncthreads();
  unsigned short* dst = Vt + (size_t)((b * 16 + h) * 64 + r) * 1024 + t0 + c0;
#pragma unroll
  for (int j = 0; j < 16; ++j) dst[j] = tile[c0 + j][r];
}

// ---------------- fused attention: 32 q-rows, 16 waves, 8-head group --------
// Wave w owns score cols [w*64, w*64+64) (2 row-tiles x 4 col-tiles in regs).
// Softmax in registers: shfl_xor over the 16 l15-lanes (which span an l4
// group's 16 cols per tile), cross-wave via RedM/RedS[32][17]. P stored to
// LDS once (bf16). PV: 16 waves = 8 tiles (2 rt x 4 dt) x split-K 2, dual
// accumulators; Yred fp32 reduce. amean in 32 plain-float regs (static idx).
__global__ __launch_bounds__(1024, 4) void attn_q32(const unsigned short* __restrict__ Qp,
                                                    const unsigned short* __restrict__ Kp,
                                                    const unsigned short* __restrict__ Vt,
                                                    unsigned short* __restrict__ Ybf,
                                                    unsigned short* __restrict__ Pmean) {
  __shared__ __align__(16) unsigned short P[32 * STR];  // 66 KB probs
  __shared__ float Yred[2][32][66];                     // 16.9 KB split-K partials
  __shared__ float RedM[32][17];
  __shared__ float RedS[32][17];
  __shared__ float invl[32];
  const int tid = threadIdx.x;
  const int w = tid >> 6, l = tid & 63;
  const int l15 = l & 15, l4 = l >> 4;
  const int bid = blockIdx.x;
  const int grp = bid & 7, qt = bid >> 3;  // grp -> XCD (bid%8 round-robin)
  const int b = grp >> 1, hg = grp & 1;
  const int q0 = qt * 32;

  float am[2][4][4];  // [rt][nt][rr]: row q0+rt*16+l4*4+rr, col w*64+nt*16+l15
#pragma unroll
  for (int rt = 0; rt < 2; ++rt)
#pragma unroll
    for (int nt = 0; nt < 4; ++nt)
#pragma unroll
      for (int rr = 0; rr < 4; ++rr) am[rt][nt][rr] = 0.f;

#pragma unroll 1
  for (int hh = 0; hh < 8; ++hh) {
    const int h = hg * 8 + hh;
    // ---- QK^T: scores stay in registers ----
    f32x4 sacc[2][4] = {};
#pragma unroll
    for (int kh = 0; kh < 2; ++kh) {
      s16x8 aq[2];
#pragma unroll
      for (int rt = 0; rt < 2; ++rt)
        aq[rt] = *(const s16x8*)&Qp[(size_t)(b * 1024 + q0 + rt * 16 + l15) * 1024 + h * 64 +
                                    kh * 32 + l4 * 8];
#pragma unroll
      for (int nt = 0; nt < 4; ++nt) {
        s16x8 kf = *(const s16x8*)&Kp[(size_t)(b * 1024 + w * 64 + nt * 16 + l15) * 1024 +
                                      h * 64 + kh * 32 + l4 * 8];
#pragma unroll
        for (int rt = 0; rt < 2; ++rt)
          sacc[rt][nt] = __builtin_amdgcn_mfma_f32_16x16x32_bf16(aq[rt], kf, sacc[rt][nt], 0, 0, 0);
      }
    }
    // ---- softmax pass 1: wave-local row max over 64 cols ----
    float mx[2][4];
#pragma unroll
    for (int rt = 0; rt < 2; ++rt)
#pragma unroll
      for (int rr = 0; rr < 4; ++rr) {
        float m0 = fmaxf(fmaxf(sacc[rt][0][rr], sacc[rt][1][rr]),
                         fmaxf(sacc[rt][2][rr], sacc[rt][3][rr]));
#pragma unroll
        for (int d = 1; d <= 8; d <<= 1) m0 = fmaxf(m0, __shfl_xor(m0, d));
        mx[rt][rr] = m0;
      }
    if (l15 == 0) {
#pragma unroll
      for (int rt = 0; rt < 2; ++rt)
#pragma unroll
        for (int rr = 0; rr < 4; ++rr) RedM[rt * 16 + l4 * 4 + rr][w] = mx[rt][rr];
    }
    __syncthreads();  // B1
    // ---- global max + exp + wave-local sum ----
    float ps[2][4];
#pragma unroll
    for (int rt = 0; rt < 2; ++rt)
#pragma unroll
      for (int rr = 0; rr < 4; ++rr) {
        float g = RedM[rt * 16 + l4 * 4 + rr][l15];
#pragma unroll
        for (int d = 1; d <= 8; d <<= 1) g = fmaxf(g, __shfl_xor(g, d));
        float s = 0.f;
#pragma unroll
        for (int nt = 0; nt < 4; ++nt) {
          float e = __expf(sacc[rt][nt][rr] - g);
          sacc[rt][nt][rr] = e;
          s += e;
        }
#pragma unroll
        for (int d = 1; d <= 8; d <<= 1) s += __shfl_xor(s, d);
        ps[rt][rr] = s;
      }
    if (l15 == 0) {
#pragma unroll
      for (int rt = 0; rt < 2; ++rt)
#pragma unroll
        for (int rr = 0; rr < 4; ++rr) RedS[rt * 16 + l4 * 4 + rr][w] = ps[rt][rr];
    }
    __syncthreads();  // B2
    // ---- global sum -> amean accumulate + P store (bf16, once) ----
#pragma unroll
    for (int rt = 0; rt < 2; ++rt)
#pragma unroll
      for (int rr = 0; rr < 4; ++rr) {
        float s = RedS[rt * 16 + l4 * 4 + rr][l15];
#pragma unroll
        for (int d = 1; d <= 8; d <<= 1) s += __shfl_xor(s, d);
        float inv = 1.0f / s;
        float fc = inv * 0.0625f;
        const int row = rt * 16 + l4 * 4 + rr;
#pragma unroll
        for (int nt = 0; nt < 4; ++nt) {
          float e = sacc[rt][nt][rr];
          am[rt][nt][rr] += e * fc;
          P[row * STR + w * 64 + nt * 16 + l15] = f2bf(e);
        }
        if (w == 0 && l15 == 0) invl[row] = inv;
      }
    __syncthreads();  // B3: P + invl ready
    // ---- P*V: wave w -> tile (rt2, dt), k-half kh2; dual accumulators ----
    {
      const int t8 = w >> 1, kh2 = w & 1;
      const int rt2 = t8 >> 2, dt = t8 & 3;
      f32x4 y0 = {}, y1 = {};
      const unsigned short* vbp =
          &Vt[(size_t)((b * 16 + h) * 64 + dt * 16 + l15) * 1024 + kh2 * 512 + l4 * 8];
      const unsigned short* pbp = &P[(rt2 * 16 + l15) * STR + kh2 * 512 + l4 * 8];
#pragma unroll
      for (int ks = 0; ks < 16; ks += 2) {
        s16x8 pa0 = *(const s16x8*)(pbp + ks * 32);
        s16x8 pa1 = *(const s16x8*)(pbp + ks * 32 + 32);
        y0 = __builtin_amdgcn_mfma_f32_16x16x32_bf16(pa0, *(const s16x8*)(vbp + ks * 32), y0, 0, 0, 0);
        y1 = __builtin_amdgcn_mfma_f32_16x16x32_bf16(pa1, *(const s16x8*)(vbp + ks * 32 + 32), y1, 0, 0, 0);
      }
      y0 += y1;
#pragma unroll
      for (int rr = 0; rr < 4; ++rr) Yred[kh2][rt2 * 16 + l4 * 4 + rr][dt * 16 + l15] = y0[rr];
    }
    __syncthreads();  // B4: Yred ready
    // ---- final Y write (bf16, packed pair) ----
    {
      const int row = tid >> 5, d0 = (tid & 31) * 2;
      float iv = invl[row];
      float a0 = (Yred[0][row][d0] + Yred[1][row][d0]) * iv;
      float a1 = (Yred[0][row][d0 + 1] + Yred[1][row][d0 + 1]) * iv;
      unsigned int pk = (unsigned int)f2bf(a0) | ((unsigned int)f2bf(a1) << 16);
      *(unsigned int*)&Ybf[(size_t)(b * 1024 + q0 + row) * 1024 + h * 64 + d0] = pk;
    }
    // no trailing barrier needed: next head's shared writes are all >= 2
    // barriers downstream of every read of this head's buffers.
  }

  // ---- head-group partial mean (scaled by 1/16) -> Pmean bf16 ----
#pragma unroll
  for (int rt = 0; rt < 2; ++rt)
#pragma unroll
    for (int rr = 0; rr < 4; ++rr) {
      const size_t rowo = (size_t)((b * 2 + hg) * 1024 + q0 + rt * 16 + l4 * 4 + rr) * 1024;
#pragma unroll
      for (int nt = 0; nt < 4; ++nt)
        Pmean[rowo + w * 64 + nt * 16 + l15] = f2bf(am[rt][nt][rr]);
    }
}

// ---------------- attm = partial[hg0] + partial[hg1] (fp32 out) ----------------
__global__ __launch_bounds__(256) void mean2(const unsigned short* __restrict__ P2,
                                             float* __restrict__ out) {
  size_t f = ((size_t)blockIdx.x * 256 + threadIdx.x) * 8;
  int b = (int)(f >> 20);
  size_t i0 = f + ((size_t)b << 20);
  s16x8 a = *(const s16x8*)&P2[i0];
  s16x8 d = *(const s16x8*)&P2[i0 + (1u << 20)];
  float4 o0, o1;
  o0.x = bf2f((unsigned short)a[0]) + bf2f((unsigned short)d[0]);
  o0.y = bf2f((unsigned short)a[1]) + bf2f((unsigned short)d[1]);
  o0.z = bf2f((unsigned short)a[2]) + bf2f((unsigned short)d[2]);
  o0.w = bf2f((unsigned short)a[3]) + bf2f((unsigned short)d[3]);
  o1.x = bf2f((unsigned short)a[4]) + bf2f((unsigned short)d[4]);
  o1.y = bf2f((unsigned short)a[5]) + bf2f((unsigned short)d[5]);
  o1.z = bf2f((unsigned short)a[6]) + bf2f((unsigned short)d[6]);
  o1.w = bf2f((unsigned short)a[7]) + bf2f((unsigned short)d[7]);
  *(float4*)&out[f] = o0;
  *(float4*)&out[f + 4] = o1;
}

// ---------------------------------------------------------------------------
extern "C" void kernel_launch(void* const* d_in, const int* in_sizes, int n_in, void* d_out,
                              int out_size, void* d_ws, size_t ws_size, hipStream_t stream) {
  const float* q_in = (const float*)d_in[0];
  const float* k_in = (const float*)d_in[1];
  const float* v_in = (const float*)d_in[2];
  const float* Wq = (const float*)d_in[3];
  const float* bq = (const float*)d_in[4];
  const float* Wk = (const float*)d_in[5];
  const float* bk = (const float*)d_in[6];
  const float* Wv = (const float*)d_in[7];
  const float* bv = (const float*)d_in[8];
  const float* Wo = (const float*)d_in[9];
  const float* bo = (const float*)d_in[10];

  float* out_y = (float*)d_out;
  float* out_att = out_y + (size_t)BT * N_EMBD;

  char* ws = (char*)d_ws;
  const size_t MB = 1024 * 1024;
  unsigned short* xin_bf = (unsigned short*)(ws);           // 3 x 8MB (q,k,v inputs bf16)
  unsigned short* W_bf = (unsigned short*)(ws + 24 * MB);   // Wo,Wq,Wk,Wv bf16
  unsigned short* Qp = (unsigned short*)(ws + 32 * MB);
  unsigned short* Kp = Qp + (size_t)BT * N_EMBD;
  unsigned short* Vp = Kp + (size_t)BT * N_EMBD;
  unsigned short* Pmean = (unsigned short*)(ws);            // [b][2][1024][1024] bf16 (16MB)
  unsigned short* Vt = (unsigned short*)(ws + 16 * MB);     // over dead v xin
  unsigned short* Ybf = Vp;                                 // over dead Vp (after transpose_v)

  const int NIN = BT * N_EMBD;     // 4M
  const int NW = N_EMBD * N_EMBD;  // 1M

  cvt_in3<<<dim3(NIN / 1024, 1, 3), 256, 0, stream>>>(q_in, k_in, v_in, xin_bf);
  cvt_w4<<<dim3(NW / 1024, 1, 4), 256, 0, stream>>>(Wo, Wq, Wk, Wv, W_bf);

  gemm_qkv<<<dim3(BT / 128, N_EMBD / 128, 3), 256, 0, stream>>>(xin_bf, W_bf, bq, bk, bv, Qp);
  transpose_v<<<dim3(16, 16, 4), 256, 0, stream>>>(Vp, Vt);
  attn_q32<<<256, 1024, 0, stream>>>(Qp, Kp, Vt, Ybf, Pmean);
  mean2<<<2048, 256, 0, stream>>>(Pmean, out_att);
  gemm_out<<<dim3(BT / 128, N_EMBD / 128), 256, 0, stream>>>(Ybf, W_bf, bo, out_y);
}

// Round 8
// 234.100 us; speedup vs baseline: 1.1516x; 1.1516x over previous
//
#include <hip/hip_runtime.h>
#include <hip/hip_fp16.h>

// ---------------------------------------------------------------------------
// MultiheadAttentionWithAttention: y = Wo(attn(Wq q, Wk k, Wv v)) + bo,
// plus head-mean attention map. B=4, T=T_MEM=1024, C=1024, H=16, hd=64.
//
// ROUND 8 = round-4 PASSING pipeline (235 us) with ONE change:
//   attn_ph2 __launch_bounds__(512,4) -> (512,2). Round-4 counters showed
//   VGPR_Count=56: the cap forced __half2 am[32] to scratch; every PV step
//   did private-mem RMW. Raising the cap to 256 registers the accumulators.
//
// Pipeline (bf16 MFMA, fp32 accum):
//   1. cvt_in3 / cvt_w4: fp32->bf16 (Wq pre-scaled by 1/8)
//   2. QKV projections: batched 128x128 gemm_bt with global_load_lds staging
//   3. transpose V to [b,h,d,t]
//   4. attn_ph2: 512 thr = 2 teams x 4 waves; block = (b, 16 q-rows, hg of 8);
//      teams process 2 heads concurrently (4 iters). Per head: QK^T ->
//      2-pass softmax (shfl-reduced) -> PV with fused head-mean accum.
//      S padded stride 1032 (conflict-free b128 reads).
//   5. mean2: attm = partial[hg0] + partial[hg1]  (fp32)
//   6. output projection -> fp32 d_out
//
// ws layout (MB), 56 MB total:
//   [0,24)  xin bf16 (q,k,v)  -> after gemm_qkv: [0,16) Pmean, [16,24) Vt
//   [24,32) W bf16 in order Wo,Wq,Wk,Wv
//   [32,56) Qp,Kp,Vp          -> Vp slot [48,56) becomes Ybf after transpose
// ---------------------------------------------------------------------------

typedef __attribute__((ext_vector_type(8))) short s16x8;
typedef __attribute__((ext_vector_type(4))) float f32x4;
typedef __attribute__((ext_vector_type(4))) unsigned short u16x4;

#define N_EMBD 1024
#define NH 16
#define BT 4096  // B*T flattened rows
#define STR 1032 // LDS score row stride (elements); 516 dwords -> conflict-free b128

#if __has_builtin(__builtin_amdgcn_global_load_lds)
#define HAVE_GLL 1
#define GLDS16(g, l)                                                              \
  __builtin_amdgcn_global_load_lds((__attribute__((address_space(1))) void*)(g), \
                                   (__attribute__((address_space(3))) void*)(l), 16, 0, 0)
#else
#define HAVE_GLL 0
#endif

static __device__ __forceinline__ unsigned short f2bf(float f) {
  unsigned int u = __builtin_bit_cast(unsigned int, f);
  u += 0x7FFFu + ((u >> 16) & 1u);  // RNE
  return (unsigned short)(u >> 16);
}
static __device__ __forceinline__ float bf2f(unsigned short h) {
  return __builtin_bit_cast(float, ((unsigned int)h) << 16);
}

// ---------------- fp32 -> bf16 converts (batched) ----------------
__global__ __launch_bounds__(256) void cvt_in3(const float* __restrict__ q,
                                               const float* __restrict__ k,
                                               const float* __restrict__ v,
                                               unsigned short* __restrict__ out) {
  const int z = blockIdx.z;
  const float* src = (z == 0) ? q : (z == 1 ? k : v);
  int i = (blockIdx.x * 256 + threadIdx.x) * 4;
  float4 val = *(const float4*)(src + i);
  u16x4 o;
  o[0] = f2bf(val.x);
  o[1] = f2bf(val.y);
  o[2] = f2bf(val.z);
  o[3] = f2bf(val.w);
  *(u16x4*)(out + (size_t)z * BT * N_EMBD + i) = o;
}

__global__ __launch_bounds__(256) void cvt_w4(const float* __restrict__ wo,
                                              const float* __restrict__ wq,
                                              const float* __restrict__ wk,
                                              const float* __restrict__ wv,
                                              unsigned short* __restrict__ out) {
  const int z = blockIdx.z;
  const float* src = (z == 0) ? wo : (z == 1 ? wq : (z == 2 ? wk : wv));
  const float scale = (z == 1) ? 0.125f : 1.0f;  // fold 1/sqrt(hd) into Wq
  int i = (blockIdx.x * 256 + threadIdx.x) * 4;
  float4 val = *(const float4*)(src + i);
  u16x4 o;
  o[0] = f2bf(val.x * scale);
  o[1] = f2bf(val.y * scale);
  o[2] = f2bf(val.z * scale);
  o[3] = f2bf(val.w * scale);
  *(u16x4*)(out + (size_t)z * N_EMBD * N_EMBD + i) = o;
}

// ---------------- 128x128 bf16 MFMA tile: C = A * B^T + bias ----------------
template <bool F32OUT>
static __device__ __forceinline__ void gemm_bt_tile(const unsigned short* __restrict__ A,
                                                    const unsigned short* __restrict__ B,
                                                    const float* __restrict__ bias, float bscale,
                                                    void* __restrict__ Cout,
                                                    int m0, int n0, int N, int K,
                                                    unsigned short* Al, unsigned short* Bl) {
  const int tid = threadIdx.x;
  const int l = tid & 63, w = tid >> 6;
  const int wr = w >> 1, wc = w & 1;
  const int l15 = l & 15, l4 = l >> 4;
  const int srow = tid >> 3;          // staging row within 32-row chunk
  const int skk = (tid & 7) * 8;      // staging k offset (16B)
  f32x4 acc[4][4] = {};
  for (int k0 = 0; k0 < K; k0 += 64) {
#if HAVE_GLL
#pragma unroll
    for (int i = 0; i < 4; ++i) {
      GLDS16(&A[(size_t)(m0 + i * 32 + srow) * K + k0 + skk], Al + i * 2048 + w * 512);
      GLDS16(&B[(size_t)(n0 + i * 32 + srow) * K + k0 + skk], Bl + i * 2048 + w * 512);
    }
#else
#pragma unroll
    for (int i = 0; i < 4; ++i) {
      int row = i * 32 + srow;
      *(s16x8*)&Al[row * 64 + skk] = *(const s16x8*)&A[(size_t)(m0 + row) * K + k0 + skk];
      *(s16x8*)&Bl[row * 64 + skk] = *(const s16x8*)&B[(size_t)(n0 + row) * K + k0 + skk];
    }
#endif
    __syncthreads();
#pragma unroll
    for (int kf = 0; kf < 2; ++kf) {
      s16x8 af[4], bfr[4];
#pragma unroll
      for (int mi = 0; mi < 4; ++mi)
        af[mi] = *(const s16x8*)&Al[(wr * 64 + mi * 16 + l15) * 64 + kf * 32 + l4 * 8];
#pragma unroll
      for (int nj = 0; nj < 4; ++nj)
        bfr[nj] = *(const s16x8*)&Bl[(wc * 64 + nj * 16 + l15) * 64 + kf * 32 + l4 * 8];
#pragma unroll
      for (int mi = 0; mi < 4; ++mi) {
#pragma unroll
        for (int nj = 0; nj < 4; ++nj)
          acc[mi][nj] =
              __builtin_amdgcn_mfma_f32_16x16x32_bf16(af[mi], bfr[nj], acc[mi][nj], 0, 0, 0);
      }
    }
    __syncthreads();
  }
#pragma unroll
  for (int nj = 0; nj < 4; ++nj) {
    int col = n0 + wc * 64 + nj * 16 + l15;
    float bv = bias[col] * bscale;
#pragma unroll
    for (int mi = 0; mi < 4; ++mi) {
#pragma unroll
      for (int r = 0; r < 4; ++r) {
        int row = m0 + wr * 64 + mi * 16 + l4 * 4 + r;
        float v = acc[mi][nj][r] + bv;
        if constexpr (F32OUT)
          ((float*)Cout)[(size_t)row * N + col] = v;
        else
          ((unsigned short*)Cout)[(size_t)row * N + col] = f2bf(v);
      }
    }
  }
}

// Batched QKV projection: grid.z selects q/k/v. Weights ordered Wo,Wq,Wk,Wv.
__global__ __launch_bounds__(256) void gemm_qkv(const unsigned short* __restrict__ Xin,
                                                const unsigned short* __restrict__ Wbf,
                                                const float* __restrict__ bq,
                                                const float* __restrict__ bk,
                                                const float* __restrict__ bv,
                                                unsigned short* __restrict__ Cout) {
  __shared__ unsigned short Al[128 * 64];
  __shared__ unsigned short Bl[128 * 64];
  const int z = blockIdx.z;
  const float* bias = (z == 0) ? bq : (z == 1 ? bk : bv);
  const float bscale = (z == 0) ? 0.125f : 1.0f;
  gemm_bt_tile<false>(Xin + (size_t)z * BT * N_EMBD,
                      Wbf + (size_t)(1 + z) * N_EMBD * N_EMBD, bias, bscale,
                      Cout + (size_t)z * BT * N_EMBD, blockIdx.x * 128, blockIdx.y * 128,
                      N_EMBD, N_EMBD, Al, Bl);
}

__global__ __launch_bounds__(256) void gemm_out(const unsigned short* __restrict__ Ybf,
                                                const unsigned short* __restrict__ Wo,
                                                const float* __restrict__ bo,
                                                float* __restrict__ Cout) {
  __shared__ unsigned short Al[128 * 64];
  __shared__ unsigned short Bl[128 * 64];
  gemm_bt_tile<true>(Ybf, Wo, bo, 1.0f, Cout, blockIdx.x * 128, blockIdx.y * 128, N_EMBD, N_EMBD,
                     Al, Bl);
}

// ---------------- V transpose: Vp[b,t,h*64+d] -> Vt[(b,h),d,t] ----------------
__global__ __launch_bounds__(256) void transpose_v(const unsigned short* __restrict__ Vp,
                                                   unsigned short* __restrict__ Vt) {
  __shared__ unsigned short tile[64][65];
  const int t0 = blockIdx.x * 64, h = blockIdx.y, b = blockIdx.z;
  const int r = threadIdx.x >> 2, c0 = (threadIdx.x & 3) * 16;
  const unsigned short* src = Vp + (size_t)(b * 1024 + t0 + r) * 1024 + h * 64 + c0;
#pragma unroll
  for (int j = 0; j < 16; ++j) tile[r][c0 + j] = src[j];
  __syncthreads();
  unsigned short* dst = Vt + (size_t)((b * 16 + h) * 64 + r) * 1024 + t0 + c0;
#pragma unroll
  for (int j = 0; j < 16; ++j) dst[j] = tile[c0 + j][r];
}

// ---------------- fused attention: 2 head-teams per block ----------------
// 512 threads = 8 waves. Team tm = tid>>8 handles head hg*8 + it*2 + tm over 4
// iterations. Per team: own score buffer S2[tm] ([16][STR=1032] bf16 padded ->
// conflict-free b128 softmax/PV reads). Softmax 2-pass, shfl + cross-wave Red.
// PV: wave w4 owns d-cols [w4*16,+16), full K; head-mean accum fused into the
// PV prob reads for the wave's k-quarter, PACKED fp16 (32 VGPRs). Team ameans
// summed fp32 at the end via the S2 region.
// launch_bounds (512,2): VGPR cap 256 so am[32] stays in registers (round-4
// counters: cap 128 -> VGPR_Count 56 -> am[] in scratch -> PV RMW chain).
__global__ __launch_bounds__(512, 2) void attn_ph2(const unsigned short* __restrict__ Qp,
                                                   const unsigned short* __restrict__ Kp,
                                                   const unsigned short* __restrict__ Vt,
                                                   unsigned short* __restrict__ Ybf,
                                                   unsigned short* __restrict__ Pmean) {
  __shared__ __align__(16) unsigned short S2[2][16 * STR];  // per-team scores/probs
  __shared__ float RedM[2][16][4];
  __shared__ float RedS[2][16][4];
  const int tid = threadIdx.x;
  const int tm = tid >> 8;               // team 0/1
  const int ttid = tid & 255;            // id within team
  const int w4 = ttid >> 6;              // wave within team
  const int l = tid & 63;
  const int l15 = l & 15, l4 = l >> 4;
  const int r = ttid & 15, c = ttid >> 4;  // softmax: row, 16-col-chunk owner

  int bid = blockIdx.x;
  int swz = (bid & 7) * 64 + (bid >> 3);  // 512 = 8 XCD chunks of 64
  int qt = swz & 63;
  int grp = swz >> 6;  // 0..7 = b*2+hg -> one per XCD
  int b = grp >> 1, hg = grp & 1;
  int q0 = qt * 16;

  // head-mean partial accumulator: 64 cells as 32 packed fp16 (v_pk_add_f16).
  // cell j = kk*8 + e  ->  col = w4*256 + kk*32 + l4*8 + e, row = l15.
  __half2 am[32];
#pragma unroll
  for (int j = 0; j < 32; ++j) am[j] = __float2half2_rn(0.f);

#pragma unroll 1
  for (int it = 0; it < 4; ++it) {
    const int h = hg * 8 + it * 2 + tm;
    // ---- QK^T: wave w4 computes score cols [w4*256, w4*256+256) ----
    const unsigned short* qbase = Qp + (size_t)(b * 1024 + q0 + l15) * 1024 + h * 64 + l4 * 8;
    s16x8 aq0 = *(const s16x8*)qbase;
    s16x8 aq1 = *(const s16x8*)(qbase + 32);
#pragma unroll
    for (int nt = 0; nt < 16; ++nt) {
      int gn = w4 * 16 + nt;
      const unsigned short* kb = Kp + (size_t)(b * 1024 + gn * 16 + l15) * 1024 + h * 64 + l4 * 8;
      f32x4 sacc = {};
      sacc = __builtin_amdgcn_mfma_f32_16x16x32_bf16(aq0, *(const s16x8*)kb, sacc, 0, 0, 0);
      sacc = __builtin_amdgcn_mfma_f32_16x16x32_bf16(aq1, *(const s16x8*)(kb + 32), sacc, 0, 0, 0);
#pragma unroll
      for (int rr = 0; rr < 4; ++rr)
        S2[tm][(l4 * 4 + rr) * STR + gn * 16 + l15] = f2bf(sacc[rr]);
    }
    __syncthreads();  // A: scores visible

    // ---- softmax pass 1: row max (thread (r,c) owns cols c*16+{kt*256}) ----
    float m = -3.4e38f;
#pragma unroll
    for (int k = 0; k < 8; ++k) {
      s16x8 sv = *(const s16x8*)&S2[tm][r * STR + c * 16 + (k >> 1) * 256 + (k & 1) * 8];
#pragma unroll
      for (int j = 0; j < 8; ++j) m = fmaxf(m, bf2f((unsigned short)sv[j]));
    }
    m = fmaxf(m, __shfl_xor(m, 16));
    m = fmaxf(m, __shfl_xor(m, 32));
    if (l < 16) RedM[tm][l][w4] = m;
    __syncthreads();  // B

    // ---- softmax pass 2: exp + writeback + sum ----
    float mm = fmaxf(fmaxf(RedM[tm][r][0], RedM[tm][r][1]),
                     fmaxf(RedM[tm][r][2], RedM[tm][r][3]));
    float ps = 0.f;
#pragma unroll
    for (int k = 0; k < 8; ++k) {
      unsigned short* sp = &S2[tm][r * STR + c * 16 + (k >> 1) * 256 + (k & 1) * 8];
      s16x8 sv = *(const s16x8*)sp;
      s16x8 pv;
#pragma unroll
      for (int j = 0; j < 8; ++j) {
        float e = __expf(bf2f((unsigned short)sv[j]) - mm);
        ps += e;
        pv[j] = (short)f2bf(e);
      }
      *(s16x8*)sp = pv;
    }
    ps += __shfl_xor(ps, 16);
    ps += __shfl_xor(ps, 32);
    if (l < 16) RedS[tm][l][w4] = ps;
    __syncthreads();  // C: probs + sums visible

    // ---- P*V: wave w4 owns d cols [w4*16, w4*16+16); amean k-quarter w4 ----
    float lsA = RedS[tm][l15][0] + RedS[tm][l15][1] + RedS[tm][l15][2] + RedS[tm][l15][3];
    float fac = 0.0625f / lsA;  // 1/(16*l) for head-mean (row l15)
    f32x4 y = {};
    const unsigned short* vb = Vt + (size_t)((b * 16 + h) * 64 + w4 * 16 + l15) * 1024 + l4 * 8;
#pragma unroll
    for (int kq = 0; kq < 4; ++kq) {
#pragma unroll
      for (int kk = 0; kk < 8; ++kk) {
        const int ks = kq * 8 + kk;
        s16x8 pa = *(const s16x8*)&S2[tm][l15 * STR + ks * 32 + l4 * 8];
        y = __builtin_amdgcn_mfma_f32_16x16x32_bf16(pa, *(const s16x8*)(vb + ks * 32), y, 0, 0, 0);
        if (kq == w4) {  // wave-uniform; static amean indices (no scratch)
#pragma unroll
          for (int e2 = 0; e2 < 4; ++e2) {
            float2 fv;
            fv.x = bf2f((unsigned short)pa[e2 * 2]) * fac;
            fv.y = bf2f((unsigned short)pa[e2 * 2 + 1]) * fac;
            am[kk * 4 + e2] = __hadd2(am[kk * 4 + e2], __float22half2_rn(fv));
          }
        }
      }
    }
#pragma unroll
    for (int rr = 0; rr < 4; ++rr) {
      int row = l4 * 4 + rr;
      float lsr = RedS[tm][row][0] + RedS[tm][row][1] + RedS[tm][row][2] + RedS[tm][row][3];
      Ybf[(size_t)(b * 1024 + q0 + row) * 1024 + h * 64 + w4 * 16 + l15] = f2bf(y[rr] / lsr);
    }
    __syncthreads();  // E: S2/Red reuse next iteration
  }

  // ---- cross-team amean reduce (fp32 add of fp16 partials) + Pmean write ----
  unsigned int* us = (unsigned int*)S2;  // 256 thr * 32 uints = 32KB, fits in S2
  if (tm == 1) {
#pragma unroll
    for (int j = 0; j < 32; ++j) us[ttid * 32 + j] = __builtin_bit_cast(unsigned int, am[j]);
  }
  __syncthreads();
  if (tm == 0) {
    unsigned short* pm =
        Pmean + (size_t)((b * 2 + hg) * 1024 + q0 + l15) * 1024 + w4 * 256 + l4 * 8;
#pragma unroll
    for (int kk = 0; kk < 8; ++kk) {
      s16x8 ov;
#pragma unroll
      for (int e2 = 0; e2 < 4; ++e2) {
        int j = kk * 4 + e2;
        __half2 ot = __builtin_bit_cast(__half2, us[ttid * 32 + j]);
        float2 fo = __half22float2(ot);
        float2 fm = __half22float2(am[j]);
        ov[e2 * 2] = (short)f2bf(fm.x + fo.x);
        ov[e2 * 2 + 1] = (short)f2bf(fm.y + fo.y);
      }
      *(s16x8*)&pm[kk * 32] = ov;
    }
  }
}

// ---------------- attm = partial[hg0] + partial[hg1] (fp32 out) ----------------
__global__ __launch_bounds__(256) void mean2(const unsigned short* __restrict__ P2,
                                             float* __restrict__ out) {
  size_t f = ((size_t)blockIdx.x * 256 + threadIdx.x) * 8;
  int b = (int)(f >> 20);
  size_t i0 = f + ((size_t)b << 20);
  s16x8 a = *(const s16x8*)&P2[i0];
  s16x8 d = *(const s16x8*)&P2[i0 + (1u << 20)];
  float4 o0, o1;
  o0.x = bf2f((unsigned short)a[0]) + bf2f((unsigned short)d[0]);
  o0.y = bf2f((unsigned short)a[1]) + bf2f((unsigned short)d[1]);
  o0.z = bf2f((unsigned short)a[2]) + bf2f((unsigned short)d[2]);
  o0.w = bf2f((unsigned short)a[3]) + bf2f((unsigned short)d[3]);
  o1.x = bf2f((unsigned short)a[4]) + bf2f((unsigned short)d[4]);
  o1.y = bf2f((unsigned short)a[5]) + bf2f((unsigned short)d[5]);
  o1.z = bf2f((unsigned short)a[6]) + bf2f((unsigned short)d[6]);
  o1.w = bf2f((unsigned short)a[7]) + bf2f((unsigned short)d[7]);
  *(float4*)&out[f] = o0;
  *(float4*)&out[f + 4] = o1;
}

// ---------------------------------------------------------------------------
extern "C" void kernel_launch(void* const* d_in, const int* in_sizes, int n_in, void* d_out,
                              int out_size, void* d_ws, size_t ws_size, hipStream_t stream) {
  const float* q_in = (const float*)d_in[0];
  const float* k_in = (const float*)d_in[1];
  const float* v_in = (const float*)d_in[2];
  const float* Wq = (const float*)d_in[3];
  const float* bq = (const float*)d_in[4];
  const float* Wk = (const float*)d_in[5];
  const float* bk = (const float*)d_in[6];
  const float* Wv = (const float*)d_in[7];
  const float* bv = (const float*)d_in[8];
  const float* Wo = (const float*)d_in[9];
  const float* bo = (const float*)d_in[10];

  float* out_y = (float*)d_out;
  float* out_att = out_y + (size_t)BT * N_EMBD;

  char* ws = (char*)d_ws;
  const size_t MB = 1024 * 1024;
  unsigned short* xin_bf = (unsigned short*)(ws);           // 3 x 8MB (q,k,v inputs bf16)
  unsigned short* W_bf = (unsigned short*)(ws + 24 * MB);   // Wo,Wq,Wk,Wv bf16
  unsigned short* Qp = (unsigned short*)(ws + 32 * MB);
  unsigned short* Kp = Qp + (size_t)BT * N_EMBD;
  unsigned short* Vp = Kp + (size_t)BT * N_EMBD;
  unsigned short* Pmean = (unsigned short*)(ws);            // [b][2][1024][1024] bf16 (16MB)
  unsigned short* Vt = (unsigned short*)(ws + 16 * MB);     // over dead v xin
  unsigned short* Ybf = Vp;                                 // over dead Vp (after transpose_v)

  const int NIN = BT * N_EMBD;     // 4M
  const int NW = N_EMBD * N_EMBD;  // 1M

  cvt_in3<<<dim3(NIN / 1024, 1, 3), 256, 0, stream>>>(q_in, k_in, v_in, xin_bf);
  cvt_w4<<<dim3(NW / 1024, 1, 4), 256, 0, stream>>>(Wo, Wq, Wk, Wv, W_bf);

  gemm_qkv<<<dim3(BT / 128, N_EMBD / 128, 3), 256, 0, stream>>>(xin_bf, W_bf, bq, bk, bv, Qp);
  transpose_v<<<dim3(16, 16, 4), 256, 0, stream>>>(Vp, Vt);
  attn_ph2<<<512, 512, 0, stream>>>(Qp, Kp, Vt, Ybf, Pmean);
  mean2<<<2048, 256, 0, stream>>>(Pmean, out_att);
  gemm_out<<<dim3(BT / 128, N_EMBD / 128), 256, 0, stream>>>(Ybf, W_bf, bo, out_y);
}